// Round 5
// baseline (1717.821 us; speedup 1.0000x reference)
//
#include <hip/hip_runtime.h>

#define N_POI 100000
#define N_EDGE 50000
#define NNZ 3200000
#define D 128

// 2-pass bucket radix sort for CSR build.
#define NBKT 196
#define SH_P2E 8
#define SH_E2P 9
#define PTILE 4000
#define PGRID 800  // NNZ / PTILE exactly
#define SCAP 256   // per-row bitonic sort capacity (row len ~Poisson(64))

__device__ inline unsigned short f2bf(float f) {  // RN-even fp32->bf16
    unsigned int u = __float_as_uint(f);
    return (unsigned short)((u + 0x7fff + ((u >> 16) & 1)) >> 16);
}
__device__ inline float bf2f(unsigned short u) {
    return __uint_as_float(((unsigned int)u) << 16);
}
__device__ inline int2 nt_int2(const int2* p) {
    unsigned long long u = __builtin_nontemporal_load((const unsigned long long*)p);
    int2 r; r.x = (int)(unsigned)(u & 0xffffffffull); r.y = (int)(unsigned)(u >> 32);
    return r;
}

// WdT[j][i] = (Wf1 @ Wpoi)[i][j],  WcT[j][i] = (Wf2 @ Wedge)[i][j]
__global__ __launch_bounds__(128) void wcombo_kernel(const float* __restrict__ Wpoi,
                                                     const float* __restrict__ Wedge,
                                                     const float* __restrict__ Wfus,
                                                     float* __restrict__ WdT,
                                                     float* __restrict__ WcT) {
    int i = blockIdx.x;
    int j = threadIdx.x;
    float s1 = 0.f, s2 = 0.f;
    for (int k = 0; k < D; ++k) {
        float f1 = Wfus[i * 256 + k];
        float f2 = Wfus[i * 256 + 128 + k];
        s1 += f1 * Wpoi[k * D + j];
        s2 += f2 * Wedge[k * D + j];
    }
    WdT[j * D + i] = s1;
    WcT[j * D + i] = s2;
}

// Y[r][c] = sum_k X[r][k] * MT[k][c].  BF16OUT: Y is bf16 (ushort), else fp32.
template <bool BF16OUT>
__global__ __launch_bounds__(256) void dense_xmT(const float* __restrict__ X,
                                                 const float* __restrict__ MT,
                                                 void* __restrict__ Yv, int nrows) {
    __shared__ float mt[D * D];
    __shared__ float xs[32 * D];
    for (int i = threadIdx.x; i < D * D / 4; i += 256)
        ((float4*)mt)[i] = ((const float4*)MT)[i];

    int ntiles = (nrows + 31) >> 5;
    int rg = threadIdx.x >> 5;
    int cg = threadIdx.x & 31;
    int r0 = rg * 4;
    int c0 = cg * 4;

    for (int tile = blockIdx.x; tile < ntiles; tile += gridDim.x) {
        int rbase = tile * 32;
        int nr = min(32, nrows - rbase);
        __syncthreads();
        for (int i = threadIdx.x; i < nr * 32; i += 256)
            ((float4*)xs)[i] = ((const float4*)(X + (size_t)rbase * D))[i];
        __syncthreads();

        float4 a0 = {0, 0, 0, 0}, a1 = {0, 0, 0, 0}, a2 = {0, 0, 0, 0}, a3 = {0, 0, 0, 0};
#pragma unroll 4
        for (int k = 0; k < D; ++k) {
            float4 m = *(const float4*)&mt[k * D + c0];
            float x0 = xs[(r0 + 0) * D + k];
            float x1 = xs[(r0 + 1) * D + k];
            float x2 = xs[(r0 + 2) * D + k];
            float x3 = xs[(r0 + 3) * D + k];
            a0.x += x0 * m.x; a0.y += x0 * m.y; a0.z += x0 * m.z; a0.w += x0 * m.w;
            a1.x += x1 * m.x; a1.y += x1 * m.y; a1.z += x1 * m.z; a1.w += x1 * m.w;
            a2.x += x2 * m.x; a2.y += x2 * m.y; a2.z += x2 * m.z; a2.w += x2 * m.w;
            a3.x += x3 * m.x; a3.y += x3 * m.y; a3.z += x3 * m.z; a3.w += x3 * m.w;
        }
        float4 accs[4] = {a0, a1, a2, a3};
#pragma unroll
        for (int t = 0; t < 4; ++t) {
            if (r0 + t < nr) {
                size_t off = (size_t)(rbase + r0 + t) * D + c0;
                if (BF16OUT) {
                    ushort4 u;
                    u.x = f2bf(accs[t].x); u.y = f2bf(accs[t].y);
                    u.z = f2bf(accs[t].z); u.w = f2bf(accs[t].w);
                    *(ushort4*)&((unsigned short*)Yv)[off] = u;
                } else {
                    *(float4*)&((float*)Yv)[off] = accs[t];
                }
            }
        }
    }
}

// ---- CSR build: 2-pass bucket radix sort ----

__global__ __launch_bounds__(256) void bkt_count(const int* __restrict__ r, int sh,
                                                 int* __restrict__ tot) {
    __shared__ int h[NBKT];
    for (int i = threadIdx.x; i < NBKT; i += 256) h[i] = 0;
    __syncthreads();
    const int4* r4 = (const int4*)r;
    const int n4 = NNZ / 4;
    for (int k = blockIdx.x * 256 + threadIdx.x; k < n4; k += gridDim.x * 256) {
        int4 rr = r4[k];
        atomicAdd(&h[rr.x >> sh], 1);
        atomicAdd(&h[rr.y >> sh], 1);
        atomicAdd(&h[rr.z >> sh], 1);
        atomicAdd(&h[rr.w >> sh], 1);
    }
    __syncthreads();
    for (int i = threadIdx.x; i < NBKT; i += 256)
        if (h[i]) atomicAdd(&tot[i], h[i]);
}

__global__ __launch_bounds__(256) void bkt_scan(const int* __restrict__ tot,
                                                int* __restrict__ base,
                                                int* __restrict__ gcur,
                                                int* __restrict__ rp, int nrows) {
    __shared__ int buf[256];
    int v = (threadIdx.x < NBKT) ? tot[threadIdx.x] : 0;
    buf[threadIdx.x] = v;
    __syncthreads();
    for (int off = 1; off < 256; off <<= 1) {
        int t = (threadIdx.x >= off) ? buf[threadIdx.x - off] : 0;
        __syncthreads();
        buf[threadIdx.x] += t;
        __syncthreads();
    }
    int excl = buf[threadIdx.x] - v;
    if (threadIdx.x < NBKT) { base[threadIdx.x] = excl; gcur[threadIdx.x] = excl; }
    if (threadIdx.x == 0) { base[NBKT] = NNZ; rp[nrows] = NNZ; }
}

__global__ __launch_bounds__(256) void partition_kernel(
    const int* __restrict__ r, const int* __restrict__ c, const float* __restrict__ v,
    int* __restrict__ gcur, int sh, int* __restrict__ rb, int2* __restrict__ cvb) {
    __shared__ int hist[NBKT];
    __shared__ int excl[NBKT];
    __shared__ int cur[NBKT];
    __shared__ int runb[NBKT];
    __shared__ int sbuf[256];
    __shared__ int rs[PTILE];
    __shared__ int2 cvs[PTILE];
    const int base = blockIdx.x * PTILE;
    for (int i = threadIdx.x; i < NBKT; i += 256) hist[i] = 0;
    __syncthreads();
    const int4* r4 = (const int4*)(r + base);
    for (int k = threadIdx.x; k < PTILE / 4; k += 256) {
        int4 rr = r4[k];
        atomicAdd(&hist[rr.x >> sh], 1);
        atomicAdd(&hist[rr.y >> sh], 1);
        atomicAdd(&hist[rr.z >> sh], 1);
        atomicAdd(&hist[rr.w >> sh], 1);
    }
    __syncthreads();
    int hv = (threadIdx.x < NBKT) ? hist[threadIdx.x] : 0;
    sbuf[threadIdx.x] = hv;
    __syncthreads();
    for (int off = 1; off < 256; off <<= 1) {
        int t = (threadIdx.x >= off) ? sbuf[threadIdx.x - off] : 0;
        __syncthreads();
        sbuf[threadIdx.x] += t;
        __syncthreads();
    }
    if (threadIdx.x < NBKT) {
        int e = sbuf[threadIdx.x] - hv;
        excl[threadIdx.x] = e;
        cur[threadIdx.x] = e;
        runb[threadIdx.x] = hv ? atomicAdd(&gcur[threadIdx.x], hv) : 0;
    }
    __syncthreads();
    const int4* c4 = (const int4*)(c + base);
    const float4* v4 = (const float4*)(v + base);
    for (int k = threadIdx.x; k < PTILE / 4; k += 256) {
        int4 rr = r4[k];
        int4 cc = c4[k];
        float4 vv = v4[k];
        int p;
        p = atomicAdd(&cur[rr.x >> sh], 1); rs[p] = rr.x; cvs[p] = make_int2(cc.x, __float_as_int(vv.x));
        p = atomicAdd(&cur[rr.y >> sh], 1); rs[p] = rr.y; cvs[p] = make_int2(cc.y, __float_as_int(vv.y));
        p = atomicAdd(&cur[rr.z >> sh], 1); rs[p] = rr.z; cvs[p] = make_int2(cc.z, __float_as_int(vv.z));
        p = atomicAdd(&cur[rr.w >> sh], 1); rs[p] = rr.w; cvs[p] = make_int2(cc.w, __float_as_int(vv.w));
    }
    __syncthreads();
    for (int p = threadIdx.x; p < PTILE; p += 256) {
        int row = rs[p];
        int b = row >> sh;
        int dst = runb[b] + (p - excl[b]);
        rb[dst] = row;
        cvb[dst] = cvs[p];
    }
}

__global__ __launch_bounds__(512) void bucket_scatter(
    const int* __restrict__ base, const int* __restrict__ rb, const int2* __restrict__ cvb,
    int sh, int nrows, int* __restrict__ rp, int2* __restrict__ cv) {
    __shared__ int cur[512];
    __shared__ int sbuf[512];
    const int b = blockIdx.x;
    const int s0 = base[b];
    const int n = base[b + 1] - s0;
    const int row0 = b << sh;
    const int nr = min(1 << sh, nrows - row0);
    for (int i = threadIdx.x; i < (1 << sh); i += 512) cur[i] = 0;
    __syncthreads();
    for (int k = threadIdx.x; k < n; k += 512)
        atomicAdd(&cur[rb[s0 + k] - row0], 1);
    __syncthreads();
    int cnt = (threadIdx.x < (1 << sh)) ? cur[threadIdx.x] : 0;
    sbuf[threadIdx.x] = cnt;
    __syncthreads();
    for (int off = 1; off < 512; off <<= 1) {
        int t = (threadIdx.x >= off) ? sbuf[threadIdx.x - off] : 0;
        __syncthreads();
        sbuf[threadIdx.x] += t;
        __syncthreads();
    }
    if (threadIdx.x < (1 << sh)) {
        int e = s0 + sbuf[threadIdx.x] - cnt;
        cur[threadIdx.x] = e;
        if (threadIdx.x < nr) rp[row0 + threadIdx.x] = e;
    }
    __syncthreads();
    for (int k = threadIdx.x; k < n; k += 512) {
        int row = rb[s0 + k];
        int p = atomicAdd(&cur[row - row0], 1);
        cv[p] = cvb[s0 + k];
    }
}

// Per-row column sort: one wave per CSR row, fixed 256-wide bitonic network in
// LDS (INT_MAX padding). All concurrently-resident spmm waves then walk their
// rows in ascending column order -> the GPU-wide gather working set becomes a
// sliding few-MB column window that stays L2-resident. Pure permutation (only
// fp sum-order changes). Rows longer than SCAP keep their tail unsorted (legal).
__global__ __launch_bounds__(512) void row_sort(const int* __restrict__ rp,
                                                int2* __restrict__ cv, int nrows) {
    __shared__ int2 buf[8][SCAP];
    int wid = threadIdx.x >> 6;
    int lane = threadIdx.x & 63;
    int row = blockIdx.x * 8 + wid;
    int s0 = 0, n = 0;
    if (row < nrows) {
        s0 = rp[row];
        n = min(rp[row + 1] - s0, SCAP);
    }
    for (int i = lane; i < SCAP; i += 64) {
        int2 v = {0x7fffffff, 0};
        if (i < n) v = cv[s0 + i];
        buf[wid][i] = v;
    }
    __syncthreads();
    for (int k = 2; k <= SCAP; k <<= 1) {
        for (int j = k >> 1; j > 0; j >>= 1) {
#pragma unroll
            for (int t = 0; t < SCAP / 64; ++t) {
                int i = lane + t * 64;
                int partner = i ^ j;
                if (partner > i) {
                    bool asc = ((i & k) == 0);
                    int2 a = buf[wid][i];
                    int2 b = buf[wid][partner];
                    if ((a.x > b.x) == asc) { buf[wid][i] = b; buf[wid][partner] = a; }
                }
            }
            __syncthreads();
        }
    }
    for (int i = lane; i < n; i += 64) cv[s0 + i] = buf[wid][i];
}

// CSR SpMM with algebraic epilogue (no RMW accumulators):
//   t = (HAS_Y ? Yinit[row] : 0) + sum val * bf16(X[col])
//   outF[row] = c0*base0[row] + (HAS_B1 ? c1*base1[row] : 0) + c2*t
//   if (HAS_OB) outb[row] = bf16(t)
template <bool HAS_Y, bool HAS_B1, bool HAS_OB>
__global__ __launch_bounds__(256) void spmm_csr_fused(
    const int* __restrict__ row_ptr, const int2* __restrict__ cv,
    const unsigned short* __restrict__ Xb, const float* __restrict__ Yinit,
    const float* __restrict__ base0, const float* __restrict__ base1,
    float* __restrict__ outF, unsigned short* __restrict__ outb,
    float c0, float c1, float c2, int nrows) {
    int row = (blockIdx.x * 256 + threadIdx.x) >> 5;
    int lane = threadIdx.x & 31;
    if (row >= nrows) return;
    int j = row_ptr[row];
    int end = row_ptr[row + 1];
    size_t off = (size_t)row * D + lane * 4;

    float4 acc = {0, 0, 0, 0};
    if (HAS_Y) acc = *(const float4*)&Yinit[off];

    for (; j + 8 <= end; j += 8) {
        int2 e[8];
#pragma unroll
        for (int t = 0; t < 8; ++t) e[t] = nt_int2(&cv[j + t]);
        ushort4 x[8];
#pragma unroll
        for (int t = 0; t < 8; ++t)
            x[t] = *(const ushort4*)&Xb[(size_t)e[t].x * D + lane * 4];
#pragma unroll
        for (int t = 0; t < 8; ++t) {
            float v = __int_as_float(e[t].y);
            acc.x += v * bf2f(x[t].x); acc.y += v * bf2f(x[t].y);
            acc.z += v * bf2f(x[t].z); acc.w += v * bf2f(x[t].w);
        }
    }
    for (; j < end; ++j) {
        int2 a = nt_int2(&cv[j]);
        float va = __int_as_float(a.y);
        ushort4 xa = *(const ushort4*)&Xb[(size_t)a.x * D + lane * 4];
        acc.x += va * bf2f(xa.x); acc.y += va * bf2f(xa.y);
        acc.z += va * bf2f(xa.z); acc.w += va * bf2f(xa.w);
    }

    float4 b0 = *(const float4*)&base0[off];
    float4 o;
    o.x = c0 * b0.x + c2 * acc.x;
    o.y = c0 * b0.y + c2 * acc.y;
    o.z = c0 * b0.z + c2 * acc.z;
    o.w = c0 * b0.w + c2 * acc.w;
    if (HAS_B1) {
        float4 b1 = *(const float4*)&base1[off];
        o.x += c1 * b1.x; o.y += c1 * b1.y; o.z += c1 * b1.z; o.w += c1 * b1.w;
    }
    *(float4*)&outF[off] = o;
    if (HAS_OB) {
        ushort4 u;
        u.x = f2bf(acc.x); u.y = f2bf(acc.y); u.z = f2bf(acc.z); u.w = f2bf(acc.w);
        *(ushort4*)&outb[off] = u;
    }
}

extern "C" void kernel_launch(void* const* d_in, const int* in_sizes, int n_in,
                              void* d_out, int out_size, void* d_ws, size_t ws_size,
                              hipStream_t stream) {
    const float* poi   = (const float*)d_in[0];
    const float* edge  = (const float*)d_in[1];
    const float* Wpoi  = (const float*)d_in[2];
    const float* Wedge = (const float*)d_in[3];
    const float* Wfus  = (const float*)d_in[4];
    const int*   p2e_row = (const int*)d_in[5];
    const int*   p2e_col = (const int*)d_in[6];
    const float* p2e_val = (const float*)d_in[7];
    const int*   e2p_row = (const int*)d_in[8];
    const int*   e2p_col = (const int*)d_in[9];
    const float* e2p_val = (const float*)d_in[10];

    float* out_poi  = (float*)d_out;
    float* out_edge = out_poi + (size_t)N_POI * D;

    char* w = (char*)d_ws;
    unsigned short* Ab = (unsigned short*)w; w += (size_t)N_POI * D * 2;   // bf16(p@Wd^T)
    float* B           = (float*)w;          w += (size_t)N_EDGE * D * 4;  // e@Wc^T (spmm1 init)
    unsigned short* Bb = (unsigned short*)w; w += (size_t)N_EDGE * D * 2;  // bf16(fused)
    float* p_cur       = (float*)w;          w += (size_t)N_POI * D * 4;   // p after layer 1
    float* e_cur       = (float*)w;          w += (size_t)N_EDGE * D * 4;  // e after layer 1
    float* WdT         = (float*)w;          w += D * D * 4;
    float* WcT         = (float*)w;          w += D * D * 4;
    int*   rp_p2e      = (int*)w;            w += ((N_EDGE + 1) * 4 + 15) / 16 * 16;
    int*   rp_e2p      = (int*)w;            w += ((N_POI + 1) * 4 + 15) / 16 * 16;
    int*   bkt_tot     = (int*)w;            w += 256 * 4;
    int*   bkt_base    = (int*)w;            w += 256 * 4;
    int*   bkt_cur     = (int*)w;            w += 256 * 4;
    int2*  cv_p2e      = (int2*)w;           w += (size_t)NNZ * 8;
    int2*  cv_e2p      = (int2*)w;           w += (size_t)NNZ * 8;

    // Staging buffers for the sort alias Ab/B (both only written inside the
    // layer loop, which runs after the builds complete).
    int*  rb_g  = (int*)Ab;   // NNZ*4 = 12.8MB <= 25.6MB (Ab)
    int2* cvb_g = (int2*)B;   // NNZ*8 = 25.6MB == 25.6MB (B)

    wcombo_kernel<<<128, 128, 0, stream>>>(Wpoi, Wedge, Wfus, WdT, WcT);

    // ---- p2e build ----
    hipMemsetAsync(bkt_tot, 0, NBKT * sizeof(int), stream);
    bkt_count<<<256, 256, 0, stream>>>(p2e_row, SH_P2E, bkt_tot);
    bkt_scan<<<1, 256, 0, stream>>>(bkt_tot, bkt_base, bkt_cur, rp_p2e, N_EDGE);
    partition_kernel<<<PGRID, 256, 0, stream>>>(p2e_row, p2e_col, p2e_val, bkt_cur,
                                                SH_P2E, rb_g, cvb_g);
    bucket_scatter<<<NBKT, 512, 0, stream>>>(bkt_base, rb_g, cvb_g, SH_P2E, N_EDGE,
                                             rp_p2e, cv_p2e);
    row_sort<<<(N_EDGE + 7) / 8, 512, 0, stream>>>(rp_p2e, cv_p2e, N_EDGE);

    // ---- e2p build (reuses staging + bucket arrays) ----
    hipMemsetAsync(bkt_tot, 0, NBKT * sizeof(int), stream);
    bkt_count<<<256, 256, 0, stream>>>(e2p_row, SH_E2P, bkt_tot);
    bkt_scan<<<1, 256, 0, stream>>>(bkt_tot, bkt_base, bkt_cur, rp_e2p, N_POI);
    partition_kernel<<<PGRID, 256, 0, stream>>>(e2p_row, e2p_col, e2p_val, bkt_cur,
                                                SH_E2P, rb_g, cvb_g);
    bucket_scatter<<<NBKT, 512, 0, stream>>>(bkt_base, rb_g, cvb_g, SH_E2P, N_POI,
                                             rp_e2p, cv_e2p);
    row_sort<<<(N_POI + 7) / 8, 512, 0, stream>>>(rp_e2p, cv_e2p, N_POI);

    const float T = 1.f / 3.f;

    // ---- layer 0 ----
    dense_xmT<true><<<512, 256, 0, stream>>>(poi, WdT, Ab, N_POI);     // Ab = bf16(p0@Wd^T)
    dense_xmT<false><<<512, 256, 0, stream>>>(edge, WcT, B, N_EDGE);   // B = e0@Wc^T
    // fused1 = B + spmm(p2e, Ab); e_cur = edge + fused1; Bb = bf16(fused1)
    spmm_csr_fused<true, false, true><<<(N_EDGE + 7) / 8, 256, 0, stream>>>(
        rp_p2e, cv_p2e, Ab, B, edge, nullptr, e_cur, Bb, 1.f, 0.f, 1.f, N_EDGE);
    // prop1 = spmm(e2p, Bb); p_cur = poi + prop1
    spmm_csr_fused<false, false, false><<<(N_POI + 7) / 8, 256, 0, stream>>>(
        rp_e2p, cv_e2p, Bb, nullptr, poi, nullptr, p_cur, nullptr, 1.f, 0.f, 1.f, N_POI);

    // ---- layer 1 (writes final outputs directly) ----
    dense_xmT<true><<<512, 256, 0, stream>>>(p_cur, WdT, Ab, N_POI);
    dense_xmT<false><<<512, 256, 0, stream>>>(e_cur, WcT, B, N_EDGE);
    // fused2 = B + spmm(p2e, Ab); out_edge = (edge + 2*e_cur + fused2)/3; Bb = bf16(fused2)
    spmm_csr_fused<true, true, true><<<(N_EDGE + 7) / 8, 256, 0, stream>>>(
        rp_p2e, cv_p2e, Ab, B, edge, e_cur, out_edge, Bb, T, 2.f * T, T, N_EDGE);
    // prop2 = spmm(e2p, Bb); out_poi = (poi + 2*p_cur + prop2)/3
    spmm_csr_fused<false, true, false><<<(N_POI + 7) / 8, 256, 0, stream>>>(
        rp_e2p, cv_e2p, Bb, nullptr, poi, p_cur, out_poi, nullptr, T, 2.f * T, T, N_POI);
}

// Round 6
// 994.336 us; speedup vs baseline: 1.7276x; 1.7276x over previous
//
#include <hip/hip_runtime.h>

#define N_POI 100000
#define N_EDGE 50000
#define NNZ 3200000
#define D 128

// 2-pass bucket radix sort for CSR build (both matrices built concurrently).
#define NBKT 196
#define SH_P2E 8
#define SH_E2P 9
#define PTILE 4000
#define PGRID 800  // NNZ / PTILE exactly

__device__ inline unsigned short f2bf(float f) {  // RN-even fp32->bf16
    unsigned int u = __float_as_uint(f);
    return (unsigned short)((u + 0x7fff + ((u >> 16) & 1)) >> 16);
}
__device__ inline float bf2f(unsigned short u) {
    return __uint_as_float(((unsigned int)u) << 16);
}
__device__ inline int2 nt_int2(const int2* p) {
    unsigned long long u = __builtin_nontemporal_load((const unsigned long long*)p);
    int2 r; r.x = (int)(unsigned)(u & 0xffffffffull); r.y = (int)(unsigned)(u >> 32);
    return r;
}
typedef float fvec4 __attribute__((ext_vector_type(4)));
__device__ inline float4 nt_ld_f4(const float* p) {
    fvec4 v = __builtin_nontemporal_load((const fvec4*)p);
    return make_float4(v[0], v[1], v[2], v[3]);
}
__device__ inline void nt_st_f4(float* p, float4 v) {
    fvec4 t; t[0] = v.x; t[1] = v.y; t[2] = v.z; t[3] = v.w;
    __builtin_nontemporal_store(t, (fvec4*)p);
}

// WdT[j][i] = (Wf1 @ Wpoi)[i][j],  WcT[j][i] = (Wf2 @ Wedge)[i][j]
__global__ __launch_bounds__(128) void wcombo_kernel(const float* __restrict__ Wpoi,
                                                     const float* __restrict__ Wedge,
                                                     const float* __restrict__ Wfus,
                                                     float* __restrict__ WdT,
                                                     float* __restrict__ WcT) {
    int i = blockIdx.x;
    int j = threadIdx.x;
    float s1 = 0.f, s2 = 0.f;
    for (int k = 0; k < D; ++k) {
        float f1 = Wfus[i * 256 + k];
        float f2 = Wfus[i * 256 + 128 + k];
        s1 += f1 * Wpoi[k * D + j];
        s2 += f2 * Wedge[k * D + j];
    }
    WdT[j * D + i] = s1;
    WcT[j * D + i] = s2;
}

// Y[r][c] = sum_k X[r][k] * MT[k][c].  BF16OUT: Y is bf16 (ushort), else fp32.
template <bool BF16OUT>
__global__ __launch_bounds__(256) void dense_xmT(const float* __restrict__ X,
                                                 const float* __restrict__ MT,
                                                 void* __restrict__ Yv, int nrows) {
    __shared__ float mt[D * D];
    __shared__ float xs[32 * D];
    for (int i = threadIdx.x; i < D * D / 4; i += 256)
        ((float4*)mt)[i] = ((const float4*)MT)[i];

    int ntiles = (nrows + 31) >> 5;
    int rg = threadIdx.x >> 5;
    int cg = threadIdx.x & 31;
    int r0 = rg * 4;
    int c0 = cg * 4;

    for (int tile = blockIdx.x; tile < ntiles; tile += gridDim.x) {
        int rbase = tile * 32;
        int nr = min(32, nrows - rbase);
        __syncthreads();
        for (int i = threadIdx.x; i < nr * 32; i += 256)
            ((float4*)xs)[i] = ((const float4*)(X + (size_t)rbase * D))[i];
        __syncthreads();

        float4 a0 = {0, 0, 0, 0}, a1 = {0, 0, 0, 0}, a2 = {0, 0, 0, 0}, a3 = {0, 0, 0, 0};
#pragma unroll 4
        for (int k = 0; k < D; ++k) {
            float4 m = *(const float4*)&mt[k * D + c0];
            float x0 = xs[(r0 + 0) * D + k];
            float x1 = xs[(r0 + 1) * D + k];
            float x2 = xs[(r0 + 2) * D + k];
            float x3 = xs[(r0 + 3) * D + k];
            a0.x += x0 * m.x; a0.y += x0 * m.y; a0.z += x0 * m.z; a0.w += x0 * m.w;
            a1.x += x1 * m.x; a1.y += x1 * m.y; a1.z += x1 * m.z; a1.w += x1 * m.w;
            a2.x += x2 * m.x; a2.y += x2 * m.y; a2.z += x2 * m.z; a2.w += x2 * m.w;
            a3.x += x3 * m.x; a3.y += x3 * m.y; a3.z += x3 * m.z; a3.w += x3 * m.w;
        }
        float4 accs[4] = {a0, a1, a2, a3};
#pragma unroll
        for (int t = 0; t < 4; ++t) {
            if (r0 + t < nr) {
                size_t off = (size_t)(rbase + r0 + t) * D + c0;
                if (BF16OUT) {
                    ushort4 u;
                    u.x = f2bf(accs[t].x); u.y = f2bf(accs[t].y);
                    u.z = f2bf(accs[t].z); u.w = f2bf(accs[t].w);
                    *(ushort4*)&((unsigned short*)Yv)[off] = u;
                } else {
                    *(float4*)&((float*)Yv)[off] = accs[t];
                }
            }
        }
    }
}

// ---- CSR build: 2-pass bucket radix sort, both matrices in each launch ----

__global__ __launch_bounds__(256) void bkt_count2(const int* __restrict__ r0,
                                                  const int* __restrict__ r1,
                                                  int* __restrict__ tot0,
                                                  int* __restrict__ tot1) {
    __shared__ int h[NBKT];
    const int half = gridDim.x >> 1;
    const bool second = blockIdx.x >= half;
    const int* r = second ? r1 : r0;
    int* tot = second ? tot1 : tot0;
    const int sh = second ? SH_E2P : SH_P2E;
    const int bid = second ? blockIdx.x - half : blockIdx.x;
    for (int i = threadIdx.x; i < NBKT; i += 256) h[i] = 0;
    __syncthreads();
    const int4* r4 = (const int4*)r;
    const int n4 = NNZ / 4;
    for (int k = bid * 256 + threadIdx.x; k < n4; k += half * 256) {
        int4 rr = r4[k];
        atomicAdd(&h[rr.x >> sh], 1);
        atomicAdd(&h[rr.y >> sh], 1);
        atomicAdd(&h[rr.z >> sh], 1);
        atomicAdd(&h[rr.w >> sh], 1);
    }
    __syncthreads();
    for (int i = threadIdx.x; i < NBKT; i += 256)
        if (h[i]) atomicAdd(&tot[i], h[i]);
}

// block 0: p2e scan; block 1: e2p scan.
__global__ __launch_bounds__(256) void bkt_scan2(const int* __restrict__ tot0,
                                                 int* __restrict__ baseA, int* __restrict__ curA,
                                                 int* __restrict__ rpA,
                                                 const int* __restrict__ tot1,
                                                 int* __restrict__ baseB, int* __restrict__ curB,
                                                 int* __restrict__ rpB) {
    __shared__ int buf[256];
    const bool second = blockIdx.x == 1;
    const int* tot = second ? tot1 : tot0;
    int* base = second ? baseB : baseA;
    int* gcur = second ? curB : curA;
    int* rp = second ? rpB : rpA;
    const int nrows = second ? N_POI : N_EDGE;
    int v = (threadIdx.x < NBKT) ? tot[threadIdx.x] : 0;
    buf[threadIdx.x] = v;
    __syncthreads();
    for (int off = 1; off < 256; off <<= 1) {
        int t = (threadIdx.x >= off) ? buf[threadIdx.x - off] : 0;
        __syncthreads();
        buf[threadIdx.x] += t;
        __syncthreads();
    }
    int excl = buf[threadIdx.x] - v;
    if (threadIdx.x < NBKT) { base[threadIdx.x] = excl; gcur[threadIdx.x] = excl; }
    if (threadIdx.x == 0) { base[NBKT] = NNZ; rp[nrows] = NNZ; }
}

// Pass 1: tile-local bucket sort in LDS, then coalesced run writeout.
__global__ __launch_bounds__(256) void partition2(
    const int* __restrict__ r0, const int* __restrict__ c0, const float* __restrict__ v0,
    int* __restrict__ gcur0, int* __restrict__ rbA, int2* __restrict__ cvbA,
    const int* __restrict__ r1, const int* __restrict__ c1, const float* __restrict__ v1,
    int* __restrict__ gcur1, int* __restrict__ rbB, int2* __restrict__ cvbB) {
    __shared__ int hist[NBKT];
    __shared__ int excl[NBKT];
    __shared__ int cur[NBKT];
    __shared__ int runb[NBKT];
    __shared__ int sbuf[256];
    __shared__ int rs[PTILE];
    __shared__ int2 cvs[PTILE];
    const bool second = blockIdx.x >= PGRID;
    const int bid = second ? blockIdx.x - PGRID : blockIdx.x;
    const int* r = second ? r1 : r0;
    const int* c = second ? c1 : c0;
    const float* v = second ? v1 : v0;
    int* gcur = second ? gcur1 : gcur0;
    int* rb = second ? rbB : rbA;
    int2* cvb = second ? cvbB : cvbA;
    const int sh = second ? SH_E2P : SH_P2E;

    const int base = bid * PTILE;
    for (int i = threadIdx.x; i < NBKT; i += 256) hist[i] = 0;
    __syncthreads();
    const int4* r4 = (const int4*)(r + base);
    for (int k = threadIdx.x; k < PTILE / 4; k += 256) {
        int4 rr = r4[k];
        atomicAdd(&hist[rr.x >> sh], 1);
        atomicAdd(&hist[rr.y >> sh], 1);
        atomicAdd(&hist[rr.z >> sh], 1);
        atomicAdd(&hist[rr.w >> sh], 1);
    }
    __syncthreads();
    int hv = (threadIdx.x < NBKT) ? hist[threadIdx.x] : 0;
    sbuf[threadIdx.x] = hv;
    __syncthreads();
    for (int off = 1; off < 256; off <<= 1) {
        int t = (threadIdx.x >= off) ? sbuf[threadIdx.x - off] : 0;
        __syncthreads();
        sbuf[threadIdx.x] += t;
        __syncthreads();
    }
    if (threadIdx.x < NBKT) {
        int e = sbuf[threadIdx.x] - hv;
        excl[threadIdx.x] = e;
        cur[threadIdx.x] = e;
        runb[threadIdx.x] = hv ? atomicAdd(&gcur[threadIdx.x], hv) : 0;
    }
    __syncthreads();
    const int4* c4 = (const int4*)(c + base);
    const float4* v4 = (const float4*)(v + base);
    for (int k = threadIdx.x; k < PTILE / 4; k += 256) {
        int4 rr = r4[k];
        int4 cc = c4[k];
        float4 vv = v4[k];
        int p;
        p = atomicAdd(&cur[rr.x >> sh], 1); rs[p] = rr.x; cvs[p] = make_int2(cc.x, __float_as_int(vv.x));
        p = atomicAdd(&cur[rr.y >> sh], 1); rs[p] = rr.y; cvs[p] = make_int2(cc.y, __float_as_int(vv.y));
        p = atomicAdd(&cur[rr.z >> sh], 1); rs[p] = rr.z; cvs[p] = make_int2(cc.z, __float_as_int(vv.z));
        p = atomicAdd(&cur[rr.w >> sh], 1); rs[p] = rr.w; cvs[p] = make_int2(cc.w, __float_as_int(vv.w));
    }
    __syncthreads();
    for (int p = threadIdx.x; p < PTILE; p += 256) {
        int row = rs[p];
        int b = row >> sh;
        int dst = runb[b] + (p - excl[b]);
        rb[dst] = row;
        cvb[dst] = cvs[p];
    }
}

// Pass 2: per-bucket block (1024 thr). Sweep 1: row hist -> row_ptr (+cursors);
// sweep 2: scatter cv within the bucket's small (L2-resident) region.
__global__ __launch_bounds__(1024) void bucket_scatter2(
    const int* __restrict__ baseA, const int* __restrict__ rbA, const int2* __restrict__ cvbA,
    int* __restrict__ rpA, int2* __restrict__ cvA,
    const int* __restrict__ baseB, const int* __restrict__ rbB, const int2* __restrict__ cvbB,
    int* __restrict__ rpB, int2* __restrict__ cvB) {
    __shared__ int cur[512];
    __shared__ int sbuf[1024];
    const bool second = blockIdx.x >= NBKT;
    const int b = second ? blockIdx.x - NBKT : blockIdx.x;
    const int* base = second ? baseB : baseA;
    const int* rb = second ? rbB : rbA;
    const int2* cvb = second ? cvbB : cvbA;
    int* rp = second ? rpB : rpA;
    int2* cv = second ? cvB : cvA;
    const int sh = second ? SH_E2P : SH_P2E;
    const int nrows = second ? N_POI : N_EDGE;

    const int s0 = base[b];
    const int n = base[b + 1] - s0;
    const int row0 = b << sh;
    const int nr = min(1 << sh, nrows - row0);
    for (int i = threadIdx.x; i < (1 << sh); i += 1024) cur[i] = 0;
    __syncthreads();
    for (int k = threadIdx.x; k < n; k += 1024)
        atomicAdd(&cur[rb[s0 + k] - row0], 1);
    __syncthreads();
    int cnt = (threadIdx.x < (1 << sh)) ? cur[threadIdx.x] : 0;
    sbuf[threadIdx.x] = cnt;
    __syncthreads();
    for (int off = 1; off < 1024; off <<= 1) {
        int t = (threadIdx.x >= off) ? sbuf[threadIdx.x - off] : 0;
        __syncthreads();
        sbuf[threadIdx.x] += t;
        __syncthreads();
    }
    if (threadIdx.x < (1 << sh)) {
        int e = s0 + sbuf[threadIdx.x] - cnt;
        cur[threadIdx.x] = e;
        if (threadIdx.x < nr) rp[row0 + threadIdx.x] = e;
    }
    __syncthreads();
    for (int k = threadIdx.x; k < n; k += 1024) {
        int row = rb[s0 + k];
        int p = atomicAdd(&cur[row - row0], 1);
        cv[p] = cvb[s0 + k];
    }
}

// CSR SpMM with algebraic epilogue (no RMW accumulators):
//   t = (HAS_Y ? Yinit[row] : 0) + sum val * bf16(X[col])
//   outF[row] = c0*base0[row] + (HAS_B1 ? c1*base1[row] : 0) + c2*t
//   if (HAS_OB) outb[row] = bf16(t)
// NTOUT: outF is final (never re-read) -> nontemporal store.
template <bool HAS_Y, bool HAS_B1, bool HAS_OB, bool NTOUT>
__global__ __launch_bounds__(256) void spmm_csr_fused(
    const int* __restrict__ row_ptr, const int2* __restrict__ cv,
    const unsigned short* __restrict__ Xb, const float* __restrict__ Yinit,
    const float* __restrict__ base0, const float* __restrict__ base1,
    float* __restrict__ outF, unsigned short* __restrict__ outb,
    float c0, float c1, float c2, int nrows) {
    int row = (blockIdx.x * 256 + threadIdx.x) >> 5;
    int lane = threadIdx.x & 31;
    if (row >= nrows) return;
    int j = row_ptr[row];
    int end = row_ptr[row + 1];
    size_t off = (size_t)row * D + lane * 4;

    float4 acc = {0, 0, 0, 0};
    if (HAS_Y) acc = nt_ld_f4(&Yinit[off]);  // read-once stream

    for (; j + 8 <= end; j += 8) {
        int2 e[8];
#pragma unroll
        for (int t = 0; t < 8; ++t) e[t] = nt_int2(&cv[j + t]);
        ushort4 x[8];
#pragma unroll
        for (int t = 0; t < 8; ++t)
            x[t] = *(const ushort4*)&Xb[(size_t)e[t].x * D + lane * 4];
#pragma unroll
        for (int t = 0; t < 8; ++t) {
            float v = __int_as_float(e[t].y);
            acc.x += v * bf2f(x[t].x); acc.y += v * bf2f(x[t].y);
            acc.z += v * bf2f(x[t].z); acc.w += v * bf2f(x[t].w);
        }
    }
    for (; j < end; ++j) {
        int2 a = nt_int2(&cv[j]);
        float va = __int_as_float(a.y);
        ushort4 xa = *(const ushort4*)&Xb[(size_t)a.x * D + lane * 4];
        acc.x += va * bf2f(xa.x); acc.y += va * bf2f(xa.y);
        acc.z += va * bf2f(xa.z); acc.w += va * bf2f(xa.w);
    }

    float4 b0 = *(const float4*)&base0[off];
    float4 o;
    o.x = c0 * b0.x + c2 * acc.x;
    o.y = c0 * b0.y + c2 * acc.y;
    o.z = c0 * b0.z + c2 * acc.z;
    o.w = c0 * b0.w + c2 * acc.w;
    if (HAS_B1) {
        float4 b1 = *(const float4*)&base1[off];
        o.x += c1 * b1.x; o.y += c1 * b1.y; o.z += c1 * b1.z; o.w += c1 * b1.w;
    }
    if (NTOUT) nt_st_f4(&outF[off], o);
    else       *(float4*)&outF[off] = o;
    if (HAS_OB) {
        ushort4 u;
        u.x = f2bf(acc.x); u.y = f2bf(acc.y); u.z = f2bf(acc.z); u.w = f2bf(acc.w);
        *(ushort4*)&outb[off] = u;  // cached: read next as gather table
    }
}

extern "C" void kernel_launch(void* const* d_in, const int* in_sizes, int n_in,
                              void* d_out, int out_size, void* d_ws, size_t ws_size,
                              hipStream_t stream) {
    const float* poi   = (const float*)d_in[0];
    const float* edge  = (const float*)d_in[1];
    const float* Wpoi  = (const float*)d_in[2];
    const float* Wedge = (const float*)d_in[3];
    const float* Wfus  = (const float*)d_in[4];
    const int*   p2e_row = (const int*)d_in[5];
    const int*   p2e_col = (const int*)d_in[6];
    const float* p2e_val = (const float*)d_in[7];
    const int*   e2p_row = (const int*)d_in[8];
    const int*   e2p_col = (const int*)d_in[9];
    const float* e2p_val = (const float*)d_in[10];

    float* out_poi  = (float*)d_out;
    float* out_edge = out_poi + (size_t)N_POI * D;

    char* w = (char*)d_ws;
    unsigned short* Ab = (unsigned short*)w; w += (size_t)N_POI * D * 2;   // bf16(p@Wd^T)
    float* B           = (float*)w;          w += (size_t)N_EDGE * D * 4;  // e@Wc^T (spmm1 init)
    unsigned short* Bb = (unsigned short*)w; w += (size_t)N_EDGE * D * 2;  // bf16(fused)
    float* p_cur       = (float*)w;          w += (size_t)N_POI * D * 4;   // p after layer 1
    float* e_cur       = (float*)w;          w += (size_t)N_EDGE * D * 4;  // e after layer 1
    float* WdT         = (float*)w;          w += D * D * 4;
    float* WcT         = (float*)w;          w += D * D * 4;
    int*   rp_p2e      = (int*)w;            w += ((N_EDGE + 1) * 4 + 15) / 16 * 16;
    int*   rp_e2p      = (int*)w;            w += ((N_POI + 1) * 4 + 15) / 16 * 16;
    int*   bkt_tot     = (int*)w;            w += 512 * 4;   // tot0 | tot1
    int*   bkt_base    = (int*)w;            w += 512 * 4;   // baseA | baseB
    int*   bkt_cur     = (int*)w;            w += 512 * 4;   // curA | curB
    int2*  cv_p2e      = (int2*)w;           w += (size_t)NNZ * 8;
    int2*  cv_e2p      = (int2*)w;           w += (size_t)NNZ * 8;

    int* tot0 = bkt_tot;        int* tot1 = bkt_tot + 256;
    int* baseA = bkt_base;      int* baseB = bkt_base + 256;
    int* curA = bkt_cur;        int* curB = bkt_cur + 256;

    // Staging buffers for the concurrent sorts alias layer-phase buffers
    // (all four are only written after the builds complete).
    int*  rbA  = (int*)Ab;     // 12.8MB <= 25.6MB
    int2* cvbA = (int2*)B;     // 25.6MB == 25.6MB
    int*  rbB  = (int*)e_cur;  // 12.8MB <= 25.6MB
    int2* cvbB = (int2*)p_cur; // 25.6MB <= 51.2MB

    wcombo_kernel<<<128, 128, 0, stream>>>(Wpoi, Wedge, Wfus, WdT, WcT);

    // ---- CSR builds (both matrices per launch) ----
    hipMemsetAsync(bkt_tot, 0, 512 * sizeof(int), stream);
    bkt_count2<<<512, 256, 0, stream>>>(p2e_row, e2p_row, tot0, tot1);
    bkt_scan2<<<2, 256, 0, stream>>>(tot0, baseA, curA, rp_p2e, tot1, baseB, curB, rp_e2p);
    partition2<<<2 * PGRID, 256, 0, stream>>>(p2e_row, p2e_col, p2e_val, curA, rbA, cvbA,
                                              e2p_row, e2p_col, e2p_val, curB, rbB, cvbB);
    bucket_scatter2<<<2 * NBKT, 1024, 0, stream>>>(baseA, rbA, cvbA, rp_p2e, cv_p2e,
                                                   baseB, rbB, cvbB, rp_e2p, cv_e2p);

    const float T = 1.f / 3.f;

    // ---- layer 0 ----
    dense_xmT<true><<<512, 256, 0, stream>>>(poi, WdT, Ab, N_POI);     // Ab = bf16(p0@Wd^T)
    dense_xmT<false><<<512, 256, 0, stream>>>(edge, WcT, B, N_EDGE);   // B = e0@Wc^T
    // fused1 = B + spmm(p2e, Ab); e_cur = edge + fused1; Bb = bf16(fused1)
    spmm_csr_fused<true, false, true, false><<<(N_EDGE + 7) / 8, 256, 0, stream>>>(
        rp_p2e, cv_p2e, Ab, B, edge, nullptr, e_cur, Bb, 1.f, 0.f, 1.f, N_EDGE);
    // prop1 = spmm(e2p, Bb); p_cur = poi + prop1
    spmm_csr_fused<false, false, false, false><<<(N_POI + 7) / 8, 256, 0, stream>>>(
        rp_e2p, cv_e2p, Bb, nullptr, poi, nullptr, p_cur, nullptr, 1.f, 0.f, 1.f, N_POI);

    // ---- layer 1 (writes final outputs directly, nontemporal) ----
    dense_xmT<true><<<512, 256, 0, stream>>>(p_cur, WdT, Ab, N_POI);
    dense_xmT<false><<<512, 256, 0, stream>>>(e_cur, WcT, B, N_EDGE);
    // fused2 = B + spmm(p2e, Ab); out_edge = (edge + 2*e_cur + fused2)/3; Bb = bf16(fused2)
    spmm_csr_fused<true, true, true, true><<<(N_EDGE + 7) / 8, 256, 0, stream>>>(
        rp_p2e, cv_p2e, Ab, B, edge, e_cur, out_edge, Bb, T, 2.f * T, T, N_EDGE);
    // prop2 = spmm(e2p, Bb); out_poi = (poi + 2*p_cur + prop2)/3
    spmm_csr_fused<false, true, false, true><<<(N_POI + 7) / 8, 256, 0, stream>>>(
        rp_e2p, cv_e2p, Bb, nullptr, poi, p_cur, out_poi, nullptr, T, 2.f * T, T, N_POI);
}

// Round 7
// 865.524 us; speedup vs baseline: 1.9847x; 1.1488x over previous
//
#include <hip/hip_runtime.h>

#define N_POI 100000
#define N_EDGE 50000
#define NNZ 3200000
#define D 128

// 2-pass bucket radix sort for CSR build (both matrices built concurrently).
#define NBKT 196
#define SH_P2E 8
#define SH_E2P 9
#define PTILE 4000
#define PGRID 800  // NNZ / PTILE exactly

__device__ inline int2 nt_int2(const int2* p) {
    unsigned long long u = __builtin_nontemporal_load((const unsigned long long*)p);
    int2 r; r.x = (int)(unsigned)(u & 0xffffffffull); r.y = (int)(unsigned)(u >> 32);
    return r;
}
typedef float fvec4 __attribute__((ext_vector_type(4)));
__device__ inline float4 nt_ld_f4(const float* p) {
    fvec4 v = __builtin_nontemporal_load((const fvec4*)p);
    return make_float4(v[0], v[1], v[2], v[3]);
}
__device__ inline void nt_st_f4(float* p, float4 v) {
    fvec4 t; t[0] = v.x; t[1] = v.y; t[2] = v.z; t[3] = v.w;
    __builtin_nontemporal_store(t, (fvec4*)p);
}
// quantize 4 floats to packed int8 with reciprocal-scale rq
__device__ inline unsigned int pk_q8(float4 a, float rq) {
    int q0 = (int)rintf(a.x * rq), q1 = (int)rintf(a.y * rq);
    int q2 = (int)rintf(a.z * rq), q3 = (int)rintf(a.w * rq);
    return (unsigned)(q0 & 255) | ((unsigned)(q1 & 255) << 8) |
           ((unsigned)(q2 & 255) << 16) | ((unsigned)(q3 & 255) << 24);
}

// WdT[j][i] = (Wf1 @ Wpoi)[i][j],  WcT[j][i] = (Wf2 @ Wedge)[i][j]
__global__ __launch_bounds__(128) void wcombo_kernel(const float* __restrict__ Wpoi,
                                                     const float* __restrict__ Wedge,
                                                     const float* __restrict__ Wfus,
                                                     float* __restrict__ WdT,
                                                     float* __restrict__ WcT) {
    int i = blockIdx.x;
    int j = threadIdx.x;
    float s1 = 0.f, s2 = 0.f;
    for (int k = 0; k < D; ++k) {
        float f1 = Wfus[i * 256 + k];
        float f2 = Wfus[i * 256 + 128 + k];
        s1 += f1 * Wpoi[k * D + j];
        s2 += f2 * Wedge[k * D + j];
    }
    WdT[j * D + i] = s1;
    WcT[j * D + i] = s2;
}

// Y[r][c] = sum_k X[r][k] * MT[k][c].
// I8OUT: Y is per-row-scaled int8 (1 byte/elem) + Ys[row] = scale; else fp32.
template <bool I8OUT>
__global__ __launch_bounds__(256) void dense_xmT(const float* __restrict__ X,
                                                 const float* __restrict__ MT,
                                                 void* __restrict__ Yv,
                                                 float* __restrict__ Ys, int nrows) {
    __shared__ float mt[D * D];
    __shared__ float xs[32 * D];
    for (int i = threadIdx.x; i < D * D / 4; i += 256)
        ((float4*)mt)[i] = ((const float4*)MT)[i];

    int ntiles = (nrows + 31) >> 5;
    int rg = threadIdx.x >> 5;
    int cg = threadIdx.x & 31;
    int r0 = rg * 4;
    int c0 = cg * 4;

    for (int tile = blockIdx.x; tile < ntiles; tile += gridDim.x) {
        int rbase = tile * 32;
        int nr = min(32, nrows - rbase);
        __syncthreads();
        for (int i = threadIdx.x; i < nr * 32; i += 256)
            ((float4*)xs)[i] = ((const float4*)(X + (size_t)rbase * D))[i];
        __syncthreads();

        float4 a0 = {0, 0, 0, 0}, a1 = {0, 0, 0, 0}, a2 = {0, 0, 0, 0}, a3 = {0, 0, 0, 0};
#pragma unroll 4
        for (int k = 0; k < D; ++k) {
            float4 m = *(const float4*)&mt[k * D + c0];
            float x0 = xs[(r0 + 0) * D + k];
            float x1 = xs[(r0 + 1) * D + k];
            float x2 = xs[(r0 + 2) * D + k];
            float x3 = xs[(r0 + 3) * D + k];
            a0.x += x0 * m.x; a0.y += x0 * m.y; a0.z += x0 * m.z; a0.w += x0 * m.w;
            a1.x += x1 * m.x; a1.y += x1 * m.y; a1.z += x1 * m.z; a1.w += x1 * m.w;
            a2.x += x2 * m.x; a2.y += x2 * m.y; a2.z += x2 * m.z; a2.w += x2 * m.w;
            a3.x += x3 * m.x; a3.y += x3 * m.y; a3.z += x3 * m.z; a3.w += x3 * m.w;
        }
        float4 accs[4] = {a0, a1, a2, a3};
        if (I8OUT) {
            // per-row absmax across the 32 col-lanes (rows of this rg group)
            float mx[4];
#pragma unroll
            for (int t = 0; t < 4; ++t)
                mx[t] = fmaxf(fmaxf(fabsf(accs[t].x), fabsf(accs[t].y)),
                              fmaxf(fabsf(accs[t].z), fabsf(accs[t].w)));
#pragma unroll
            for (int d = 1; d < 32; d <<= 1) {
#pragma unroll
                for (int t = 0; t < 4; ++t) mx[t] = fmaxf(mx[t], __shfl_xor(mx[t], d, 32));
            }
#pragma unroll
            for (int t = 0; t < 4; ++t) {
                if (r0 + t < nr) {
                    float m = mx[t];
                    float s = (m > 0.f) ? m * (1.f / 127.f) : 1.f;
                    float rq = (m > 0.f) ? 127.f / m : 0.f;
                    *(unsigned int*)&((unsigned char*)Yv)[(size_t)(rbase + r0 + t) * D + c0] =
                        pk_q8(accs[t], rq);
                    if (cg == 0) Ys[rbase + r0 + t] = s;
                }
            }
        } else {
#pragma unroll
            for (int t = 0; t < 4; ++t) {
                if (r0 + t < nr) {
                    size_t off = (size_t)(rbase + r0 + t) * D + c0;
                    *(float4*)&((float*)Yv)[off] = accs[t];
                }
            }
        }
    }
}

// ---- CSR build: 2-pass bucket radix sort, both matrices in each launch ----

__global__ __launch_bounds__(256) void bkt_count2(const int* __restrict__ r0,
                                                  const int* __restrict__ r1,
                                                  int* __restrict__ tot0,
                                                  int* __restrict__ tot1) {
    __shared__ int h[NBKT];
    const int half = gridDim.x >> 1;
    const bool second = blockIdx.x >= half;
    const int* r = second ? r1 : r0;
    int* tot = second ? tot1 : tot0;
    const int sh = second ? SH_E2P : SH_P2E;
    const int bid = second ? blockIdx.x - half : blockIdx.x;
    for (int i = threadIdx.x; i < NBKT; i += 256) h[i] = 0;
    __syncthreads();
    const int4* r4 = (const int4*)r;
    const int n4 = NNZ / 4;
    for (int k = bid * 256 + threadIdx.x; k < n4; k += half * 256) {
        int4 rr = r4[k];
        atomicAdd(&h[rr.x >> sh], 1);
        atomicAdd(&h[rr.y >> sh], 1);
        atomicAdd(&h[rr.z >> sh], 1);
        atomicAdd(&h[rr.w >> sh], 1);
    }
    __syncthreads();
    for (int i = threadIdx.x; i < NBKT; i += 256)
        if (h[i]) atomicAdd(&tot[i], h[i]);
}

__global__ __launch_bounds__(256) void bkt_scan2(const int* __restrict__ tot0,
                                                 int* __restrict__ baseA, int* __restrict__ curA,
                                                 int* __restrict__ rpA,
                                                 const int* __restrict__ tot1,
                                                 int* __restrict__ baseB, int* __restrict__ curB,
                                                 int* __restrict__ rpB) {
    __shared__ int buf[256];
    const bool second = blockIdx.x == 1;
    const int* tot = second ? tot1 : tot0;
    int* base = second ? baseB : baseA;
    int* gcur = second ? curB : curA;
    int* rp = second ? rpB : rpA;
    const int nrows = second ? N_POI : N_EDGE;
    int v = (threadIdx.x < NBKT) ? tot[threadIdx.x] : 0;
    buf[threadIdx.x] = v;
    __syncthreads();
    for (int off = 1; off < 256; off <<= 1) {
        int t = (threadIdx.x >= off) ? buf[threadIdx.x - off] : 0;
        __syncthreads();
        buf[threadIdx.x] += t;
        __syncthreads();
    }
    int excl = buf[threadIdx.x] - v;
    if (threadIdx.x < NBKT) { base[threadIdx.x] = excl; gcur[threadIdx.x] = excl; }
    if (threadIdx.x == 0) { base[NBKT] = NNZ; rp[nrows] = NNZ; }
}

__global__ __launch_bounds__(256) void partition2(
    const int* __restrict__ r0, const int* __restrict__ c0, const float* __restrict__ v0,
    int* __restrict__ gcur0, int* __restrict__ rbA, int2* __restrict__ cvbA,
    const int* __restrict__ r1, const int* __restrict__ c1, const float* __restrict__ v1,
    int* __restrict__ gcur1, int* __restrict__ rbB, int2* __restrict__ cvbB) {
    __shared__ int hist[NBKT];
    __shared__ int excl[NBKT];
    __shared__ int cur[NBKT];
    __shared__ int runb[NBKT];
    __shared__ int sbuf[256];
    __shared__ int rs[PTILE];
    __shared__ int2 cvs[PTILE];
    const bool second = blockIdx.x >= PGRID;
    const int bid = second ? blockIdx.x - PGRID : blockIdx.x;
    const int* r = second ? r1 : r0;
    const int* c = second ? c1 : c0;
    const float* v = second ? v1 : v0;
    int* gcur = second ? gcur1 : gcur0;
    int* rb = second ? rbB : rbA;
    int2* cvb = second ? cvbB : cvbA;
    const int sh = second ? SH_E2P : SH_P2E;

    const int base = bid * PTILE;
    for (int i = threadIdx.x; i < NBKT; i += 256) hist[i] = 0;
    __syncthreads();
    const int4* r4 = (const int4*)(r + base);
    for (int k = threadIdx.x; k < PTILE / 4; k += 256) {
        int4 rr = r4[k];
        atomicAdd(&hist[rr.x >> sh], 1);
        atomicAdd(&hist[rr.y >> sh], 1);
        atomicAdd(&hist[rr.z >> sh], 1);
        atomicAdd(&hist[rr.w >> sh], 1);
    }
    __syncthreads();
    int hv = (threadIdx.x < NBKT) ? hist[threadIdx.x] : 0;
    sbuf[threadIdx.x] = hv;
    __syncthreads();
    for (int off = 1; off < 256; off <<= 1) {
        int t = (threadIdx.x >= off) ? sbuf[threadIdx.x - off] : 0;
        __syncthreads();
        sbuf[threadIdx.x] += t;
        __syncthreads();
    }
    if (threadIdx.x < NBKT) {
        int e = sbuf[threadIdx.x] - hv;
        excl[threadIdx.x] = e;
        cur[threadIdx.x] = e;
        runb[threadIdx.x] = hv ? atomicAdd(&gcur[threadIdx.x], hv) : 0;
    }
    __syncthreads();
    const int4* c4 = (const int4*)(c + base);
    const float4* v4 = (const float4*)(v + base);
    for (int k = threadIdx.x; k < PTILE / 4; k += 256) {
        int4 rr = r4[k];
        int4 cc = c4[k];
        float4 vv = v4[k];
        int p;
        p = atomicAdd(&cur[rr.x >> sh], 1); rs[p] = rr.x; cvs[p] = make_int2(cc.x, __float_as_int(vv.x));
        p = atomicAdd(&cur[rr.y >> sh], 1); rs[p] = rr.y; cvs[p] = make_int2(cc.y, __float_as_int(vv.y));
        p = atomicAdd(&cur[rr.z >> sh], 1); rs[p] = rr.z; cvs[p] = make_int2(cc.z, __float_as_int(vv.z));
        p = atomicAdd(&cur[rr.w >> sh], 1); rs[p] = rr.w; cvs[p] = make_int2(cc.w, __float_as_int(vv.w));
    }
    __syncthreads();
    for (int p = threadIdx.x; p < PTILE; p += 256) {
        int row = rs[p];
        int b = row >> sh;
        int dst = runb[b] + (p - excl[b]);
        rb[dst] = row;
        cvb[dst] = cvs[p];
    }
}

__global__ __launch_bounds__(1024) void bucket_scatter2(
    const int* __restrict__ baseA, const int* __restrict__ rbA, const int2* __restrict__ cvbA,
    int* __restrict__ rpA, int2* __restrict__ cvA,
    const int* __restrict__ baseB, const int* __restrict__ rbB, const int2* __restrict__ cvbB,
    int* __restrict__ rpB, int2* __restrict__ cvB) {
    __shared__ int cur[512];
    __shared__ int sbuf[1024];
    const bool second = blockIdx.x >= NBKT;
    const int b = second ? blockIdx.x - NBKT : blockIdx.x;
    const int* base = second ? baseB : baseA;
    const int* rb = second ? rbB : rbA;
    const int2* cvb = second ? cvbB : cvbA;
    int* rp = second ? rpB : rpA;
    int2* cv = second ? cvB : cvA;
    const int sh = second ? SH_E2P : SH_P2E;
    const int nrows = second ? N_POI : N_EDGE;

    const int s0 = base[b];
    const int n = base[b + 1] - s0;
    const int row0 = b << sh;
    const int nr = min(1 << sh, nrows - row0);
    for (int i = threadIdx.x; i < (1 << sh); i += 1024) cur[i] = 0;
    __syncthreads();
    for (int k = threadIdx.x; k < n; k += 1024)
        atomicAdd(&cur[rb[s0 + k] - row0], 1);
    __syncthreads();
    int cnt = (threadIdx.x < (1 << sh)) ? cur[threadIdx.x] : 0;
    sbuf[threadIdx.x] = cnt;
    __syncthreads();
    for (int off = 1; off < 1024; off <<= 1) {
        int t = (threadIdx.x >= off) ? sbuf[threadIdx.x - off] : 0;
        __syncthreads();
        sbuf[threadIdx.x] += t;
        __syncthreads();
    }
    if (threadIdx.x < (1 << sh)) {
        int e = s0 + sbuf[threadIdx.x] - cnt;
        cur[threadIdx.x] = e;
        if (threadIdx.x < nr) rp[row0 + threadIdx.x] = e;
    }
    __syncthreads();
    for (int k = threadIdx.x; k < n; k += 1024) {
        int row = rb[s0 + k];
        int p = atomicAdd(&cur[row - row0], 1);
        cv[p] = cvb[s0 + k];
    }
}

// CSR SpMM over per-row-scaled int8 gather payload, fp32 accumulate:
//   t = (HAS_Y ? Yinit[row] : 0) + sum val * (Xs[col] * i8(Xq[col][:]))
//   outF[row] = c0*base0[row] + (HAS_B1 ? c1*base1[row] : 0) + c2*t
//   if (HAS_OB) { outb[row] = i8(t), outs[row] = scale }
template <bool HAS_Y, bool HAS_B1, bool HAS_OB, bool NTOUT>
__global__ __launch_bounds__(256) void spmm_csr_fused(
    const int* __restrict__ row_ptr, const int2* __restrict__ cv,
    const unsigned char* __restrict__ Xq, const float* __restrict__ Xs,
    const float* __restrict__ Yinit,
    const float* __restrict__ base0, const float* __restrict__ base1,
    float* __restrict__ outF, unsigned char* __restrict__ outb,
    float* __restrict__ outs, float c0, float c1, float c2, int nrows) {
    int row = (blockIdx.x * 256 + threadIdx.x) >> 5;
    int lane = threadIdx.x & 31;
    if (row >= nrows) return;
    int j = row_ptr[row];
    int end = row_ptr[row + 1];
    size_t off = (size_t)row * D + lane * 4;

    float4 acc = {0, 0, 0, 0};
    if (HAS_Y) acc = nt_ld_f4(&Yinit[off]);  // read-once stream

    for (; j + 8 <= end; j += 8) {
        int2 e[8];
#pragma unroll
        for (int t = 0; t < 8; ++t) e[t] = nt_int2(&cv[j + t]);
        unsigned int x[8];
        float sv[8];
#pragma unroll
        for (int t = 0; t < 8; ++t) {
            x[t] = *(const unsigned int*)&Xq[(size_t)e[t].x * D + lane * 4];
            sv[t] = __int_as_float(e[t].y) * Xs[e[t].x];
        }
#pragma unroll
        for (int t = 0; t < 8; ++t) {
            float v = sv[t];
            acc.x += v * (float)(signed char)(x[t]);
            acc.y += v * (float)(signed char)(x[t] >> 8);
            acc.z += v * (float)(signed char)(x[t] >> 16);
            acc.w += v * (float)(signed char)(x[t] >> 24);
        }
    }
    for (; j < end; ++j) {
        int2 a = nt_int2(&cv[j]);
        unsigned int xa = *(const unsigned int*)&Xq[(size_t)a.x * D + lane * 4];
        float va = __int_as_float(a.y) * Xs[a.x];
        acc.x += va * (float)(signed char)(xa);
        acc.y += va * (float)(signed char)(xa >> 8);
        acc.z += va * (float)(signed char)(xa >> 16);
        acc.w += va * (float)(signed char)(xa >> 24);
    }

    float4 b0 = *(const float4*)&base0[off];
    float4 o;
    o.x = c0 * b0.x + c2 * acc.x;
    o.y = c0 * b0.y + c2 * acc.y;
    o.z = c0 * b0.z + c2 * acc.z;
    o.w = c0 * b0.w + c2 * acc.w;
    if (HAS_B1) {
        float4 b1 = *(const float4*)&base1[off];
        o.x += c1 * b1.x; o.y += c1 * b1.y; o.z += c1 * b1.z; o.w += c1 * b1.w;
    }
    if (NTOUT) nt_st_f4(&outF[off], o);
    else       *(float4*)&outF[off] = o;
    if (HAS_OB) {
        float m = fmaxf(fmaxf(fabsf(acc.x), fabsf(acc.y)), fmaxf(fabsf(acc.z), fabsf(acc.w)));
#pragma unroll
        for (int d = 1; d < 32; d <<= 1) m = fmaxf(m, __shfl_xor(m, d, 32));
        float s = (m > 0.f) ? m * (1.f / 127.f) : 1.f;
        float rq = (m > 0.f) ? 127.f / m : 0.f;
        *(unsigned int*)&outb[off] = pk_q8(acc, rq);
        if (lane == 0) outs[row] = s;
    }
}

extern "C" void kernel_launch(void* const* d_in, const int* in_sizes, int n_in,
                              void* d_out, int out_size, void* d_ws, size_t ws_size,
                              hipStream_t stream) {
    const float* poi   = (const float*)d_in[0];
    const float* edge  = (const float*)d_in[1];
    const float* Wpoi  = (const float*)d_in[2];
    const float* Wedge = (const float*)d_in[3];
    const float* Wfus  = (const float*)d_in[4];
    const int*   p2e_row = (const int*)d_in[5];
    const int*   p2e_col = (const int*)d_in[6];
    const float* p2e_val = (const float*)d_in[7];
    const int*   e2p_row = (const int*)d_in[8];
    const int*   e2p_col = (const int*)d_in[9];
    const float* e2p_val = (const float*)d_in[10];

    float* out_poi  = (float*)d_out;
    float* out_edge = out_poi + (size_t)N_POI * D;

    char* w = (char*)d_ws;
    unsigned char* Ab = (unsigned char*)w; w += (size_t)N_POI * D * 2;     // i8(p@Wd^T) (slot kept 2B/elem for aliasing)
    float* B           = (float*)w;        w += (size_t)N_EDGE * D * 4;    // e@Wc^T (spmm1 init)
    unsigned char* Bb  = (unsigned char*)w; w += (size_t)N_EDGE * D * 2;   // i8(fused)
    float* p_cur       = (float*)w;        w += (size_t)N_POI * D * 4;     // p after layer 1
    float* e_cur       = (float*)w;        w += (size_t)N_EDGE * D * 4;    // e after layer 1
    float* WdT         = (float*)w;        w += D * D * 4;
    float* WcT         = (float*)w;        w += D * D * 4;
    int*   rp_p2e      = (int*)w;          w += ((N_EDGE + 1) * 4 + 15) / 16 * 16;
    int*   rp_e2p      = (int*)w;          w += ((N_POI + 1) * 4 + 15) / 16 * 16;
    int*   bkt_tot     = (int*)w;          w += 512 * 4;   // tot0 | tot1
    int*   bkt_base    = (int*)w;          w += 512 * 4;   // baseA | baseB
    int*   bkt_cur     = (int*)w;          w += 512 * 4;   // curA | curB
    float* sA          = (float*)w;        w += (size_t)N_POI * 4;   // row scales for Ab
    float* sB          = (float*)w;        w += (size_t)N_EDGE * 4;  // row scales for Bb
    int2*  cv_p2e      = (int2*)w;         w += (size_t)NNZ * 8;
    int2*  cv_e2p      = (int2*)w;         w += (size_t)NNZ * 8;

    int* tot0 = bkt_tot;        int* tot1 = bkt_tot + 256;
    int* baseA = bkt_base;      int* baseB = bkt_base + 256;
    int* curA = bkt_cur;        int* curB = bkt_cur + 256;

    // Staging buffers for the concurrent sorts alias layer-phase buffers
    // (all four are only written after the builds complete).
    int*  rbA  = (int*)Ab;     // 12.8MB <= 25.6MB slot
    int2* cvbA = (int2*)B;     // 25.6MB == 25.6MB
    int*  rbB  = (int*)e_cur;  // 12.8MB <= 25.6MB
    int2* cvbB = (int2*)p_cur; // 25.6MB <= 51.2MB

    wcombo_kernel<<<128, 128, 0, stream>>>(Wpoi, Wedge, Wfus, WdT, WcT);

    // ---- CSR builds (both matrices per launch) ----
    hipMemsetAsync(bkt_tot, 0, 512 * sizeof(int), stream);
    bkt_count2<<<512, 256, 0, stream>>>(p2e_row, e2p_row, tot0, tot1);
    bkt_scan2<<<2, 256, 0, stream>>>(tot0, baseA, curA, rp_p2e, tot1, baseB, curB, rp_e2p);
    partition2<<<2 * PGRID, 256, 0, stream>>>(p2e_row, p2e_col, p2e_val, curA, rbA, cvbA,
                                              e2p_row, e2p_col, e2p_val, curB, rbB, cvbB);
    bucket_scatter2<<<2 * NBKT, 1024, 0, stream>>>(baseA, rbA, cvbA, rp_p2e, cv_p2e,
                                                   baseB, rbB, cvbB, rp_e2p, cv_e2p);

    const float T = 1.f / 3.f;

    // ---- layer 0 ----
    dense_xmT<true><<<512, 256, 0, stream>>>(poi, WdT, Ab, sA, N_POI);      // Ab,sA = i8(p0@Wd^T)
    dense_xmT<false><<<512, 256, 0, stream>>>(edge, WcT, B, nullptr, N_EDGE); // B = e0@Wc^T
    // fused1 = B + spmm(p2e, Ab); e_cur = edge + fused1; Bb,sB = i8(fused1)
    spmm_csr_fused<true, false, true, false><<<(N_EDGE + 7) / 8, 256, 0, stream>>>(
        rp_p2e, cv_p2e, Ab, sA, B, edge, nullptr, e_cur, Bb, sB, 1.f, 0.f, 1.f, N_EDGE);
    // prop1 = spmm(e2p, Bb); p_cur = poi + prop1
    spmm_csr_fused<false, false, false, false><<<(N_POI + 7) / 8, 256, 0, stream>>>(
        rp_e2p, cv_e2p, Bb, sB, nullptr, poi, nullptr, p_cur, nullptr, nullptr,
        1.f, 0.f, 1.f, N_POI);

    // ---- layer 1 (writes final outputs directly, nontemporal) ----
    dense_xmT<true><<<512, 256, 0, stream>>>(p_cur, WdT, Ab, sA, N_POI);
    dense_xmT<false><<<512, 256, 0, stream>>>(e_cur, WcT, B, nullptr, N_EDGE);
    // fused2 = B + spmm(p2e, Ab); out_edge = (edge + 2*e_cur + fused2)/3; Bb,sB = i8(fused2)
    spmm_csr_fused<true, true, true, true><<<(N_EDGE + 7) / 8, 256, 0, stream>>>(
        rp_p2e, cv_p2e, Ab, sA, B, edge, e_cur, out_edge, Bb, sB, T, 2.f * T, T, N_EDGE);
    // prop2 = spmm(e2p, Bb); out_poi = (poi + 2*p_cur + prop2)/3
    spmm_csr_fused<false, true, false, true><<<(N_POI + 7) / 8, 256, 0, stream>>>(
        rp_e2p, cv_e2p, Bb, sB, nullptr, poi, p_cur, out_poi, nullptr, nullptr,
        T, 2.f * T, T, N_POI);
}